// Round 21
// baseline (89.942 us; speedup 1.0000x reference)
//
#include <hip/hip_runtime.h>
#include <hip/hip_bf16.h>
#include <math.h>

// Problem constants
#define U_   300
#define K_   19
#define FC_  100
#define B_   256
#define L_   1000
#define P_   140     // pooled length
#define EPS_ 1e-5f
#define WLD_ 144     // fc LDS row stride (bf16): 288 B, 16-B aligned

typedef unsigned short ushort_t;
typedef __attribute__((ext_vector_type(8)))  short short8v;   // 8 bf16 = 4 VGPR
typedef __attribute__((ext_vector_type(16))) float f32x16;    // MFMA 32x32 acc

// f32 -> bf16 round-to-nearest-even (bit trick)
__device__ __forceinline__ ushort_t f2bf(float f) {
    union { float f; unsigned u; } a; a.f = f;
    unsigned r = a.u + 0x7fffu + ((a.u >> 16) & 1u);
    return (ushort_t)(r >> 16);
}

// ---------------------------------------------------------------------------
// pack_conv_k: conv weights -> bf16, BN1 scale folded, LANE-LINEAR tile layout:
//   element offset = nt*2560 + kc*512 + half*256 + r*8 + e
// (u = nt*32 + r, GEMM-k j = kc*16 + half*8 + e, j order = 4*t + d).
// Lane (half*32+r) reads its 16 B at byte offset lane*16 in the (nt,kc) slab.
// ---------------------------------------------------------------------------
__global__ __launch_bounds__(256, 4)
void pack_conv_k(const float* __restrict__ w_conv, const float* __restrict__ b_conv,
                 const float* __restrict__ g1, const float* __restrict__ be1,
                 const float* __restrict__ m1, const float* __restrict__ v1,
                 ushort_t* __restrict__ w_bf, float* __restrict__ o1g)
{
    const int t = blockIdx.x * 256 + threadIdx.x;
    if (t < 320 * 80) {
        const int u = t / 80, j = t - u * 80;
        float val = 0.f;
        if (u < U_ && j < 76) {
            const int tp = j >> 2;          // kernel position 0..18
            const int d  = j & 3;           // DNA channel 0..3
            const float s1 = g1[u] / sqrtf(v1[u] + EPS_);
            val = w_conv[u * 76 + 19 * d + tp] * s1;
        }
        const int nt = u >> 5, r = u & 31;
        const int kc = j >> 4, rem = j & 15;
        const int half = rem >> 3, e = rem & 7;
        w_bf[nt * 2560 + kc * 512 + half * 256 + r * 8 + e] = f2bf(val);
    }
    if (t < 320) {
        float o = 0.f;
        if (t < U_) {
            const float s1 = g1[t] / sqrtf(v1[t] + EPS_);
            o = (b_conv[t] - m1[t]) * s1 + be1[t];
        }
        o1g[t] = o;
    }
}

// ---------------------------------------------------------------------------
// conv_mfma_k R21: B-REUSE x4 -- four batches per wave share each B-fragment.
// Theory: all prior variants delivered ~1 KB of B per MFMA to every wave
// (L2 broadcast 115-460 MB -> 10-30us, or 51-KB LDS stage -> 2 blocks/CU).
// Here each wave loads 5 B-frags per ntp ONCE and runs FOUR independent
// MFMA chains (acc0..3) against 4 LDS-staged batches: B traffic /4, MFMA
// dependency distance 4 (self-hiding), per-wave issue density x4.
// 256 thr = 4 waves = 4 m-tiles (4 windows each); grid (9 bx, 2 nh, 64 bg).
// LDS ~13 KB (x4 batches 8.7 KB + stage 4.2 KB); ~115 VGPR; 4 blocks/CU.
// In-register pooling via row permutation; per-ntp stage + coalesced drain.
// ---------------------------------------------------------------------------
__global__ __launch_bounds__(256, 4)
void conv_mfma_k(const float4* __restrict__ x4,        // (B,1000) float4 (D=4)
                 const ushort_t* __restrict__ w_bf,    // packed tiles (see pack)
                 const float* __restrict__ o1g,        // (320)
                 ushort_t* __restrict__ pooled)        // (U,B,P) bf16
{
    __shared__ ushort_t xls[4][544];     // 4 batches x 136 rows x 4 ushorts
    __shared__ ushort_t stage[32][66];   // [u-local][bat*16 + window], pad 2
    const int tid = threadIdx.x;
    const int bx  = blockIdx.x;          // 0..8
    const int nh  = blockIdx.y;          // 0/1 -> nt range [5nh, 5nh+5)
    const int b0  = 4 * blockIdx.z;      // batches b0..b0+3
    const int w0  = bx * 16;             // first window of block
    const int l0  = w0 * 7;              // first conv row (112*bx, max 896)

    // stage x rows for 4 batches (136 rows each; guard past L)
    for (int i = tid; i < 544; i += 256) {
        const int bat = i / 136, row = i - bat * 136;
        const int gi = l0 + row;
        float4 v = make_float4(0.f, 0.f, 0.f, 0.f);
        if (gi < L_) v = x4[(size_t)(b0 + bat) * L_ + gi];
        ushort4 pk4;
        pk4.x = f2bf(v.x); pk4.y = f2bf(v.y); pk4.z = f2bf(v.z); pk4.w = f2bf(v.w);
        *(ushort4*)&xls[bat][4 * row] = pk4;
    }
    __syncthreads();

    const int lane = tid & 63;
    const int wv   = tid >> 6;           // m-tile 0..3 (windows 4wv..4wv+3)
    const int half = lane >> 5;
    const int r32  = lane & 31;

    // permuted A-row offset for slot r32 (two 7-row pool windows per
    // lane-half's C slots; spares at sreg 14,15)
    const int sreg = (r32 & 3) + 4 * (r32 >> 3);
    const int sh   = (r32 >> 2) & 1;
    const int off  = sreg < 7  ? sreg + 7 * sh
                   : sreg < 14 ? sreg + 7 + 7 * sh
                               : 28 + (sreg - 14) + 2 * sh;

    const int xoffb = 8 * (28 * wv + off) + 16 * half;  // byte offset per batch
    const char* xb0 = (const char*)&xls[0][0] + xoffb;
    const char* xb1 = (const char*)&xls[1][0] + xoffb;
    const char* xb2 = (const char*)&xls[2][0] + xoffb;
    const char* xb3 = (const char*)&xls[3][0] + xoffb;

    // lane-linear B base in the packed global table (L2-resident, 51 KB)
    const char* wgl = (const char*)w_bf + nh * 5 * 5120 + 16 * lane;

    const int p0off = 4 * wv + half;     // stage cols (per batch) p0off, p0off+2

    for (int ntp = 0; ntp < 5; ++ntp) {
        short8v bfr[5];
#pragma unroll
        for (int kc = 0; kc < 5; ++kc)
            bfr[kc] = *(const short8v*)(wgl + ntp * 5120 + kc * 1024);
        const int ubase = nh * 160 + ntp * 32;
        const float o1u = o1g[ubase + r32];

        f32x16 acc0 = {}, acc1 = {}, acc2 = {}, acc3 = {};
#pragma unroll
        for (int kc = 0; kc < 5; ++kc) {
            const short8v a0 = *(const short8v*)(xb0 + 32 * kc);
            const short8v a1 = *(const short8v*)(xb1 + 32 * kc);
            const short8v a2 = *(const short8v*)(xb2 + 32 * kc);
            const short8v a3 = *(const short8v*)(xb3 + 32 * kc);
            acc0 = __builtin_amdgcn_mfma_f32_32x32x16_bf16(a0, bfr[kc], acc0, 0, 0, 0);
            acc1 = __builtin_amdgcn_mfma_f32_32x32x16_bf16(a1, bfr[kc], acc1, 0, 0, 0);
            acc2 = __builtin_amdgcn_mfma_f32_32x32x16_bf16(a2, bfr[kc], acc2, 0, 0, 0);
            acc3 = __builtin_amdgcn_mfma_f32_32x32x16_bf16(a3, bfr[kc], acc3, 0, 0, 0);
        }

        // in-register pooling, 4 batches (o1 added after max; exp monotone)
#define POOL_STORE(ACC, BAT)                                                   \
        {                                                                      \
            float m0 = ACC[0], m1 = ACC[7];                                    \
            _Pragma("unroll")                                                  \
            for (int j = 1; j < 7; ++j)  m0 = fmaxf(m0, ACC[j]);               \
            _Pragma("unroll")                                                  \
            for (int j = 8; j < 14; ++j) m1 = fmaxf(m1, ACC[j]);               \
            stage[r32][(BAT) * 16 + p0off]     = f2bf(__expf(m0 + o1u));       \
            stage[r32][(BAT) * 16 + p0off + 2] = f2bf(__expf(m1 + o1u));       \
        }
        POOL_STORE(acc0, 0)
        POOL_STORE(acc1, 1)
        POOL_STORE(acc2, 2)
        POOL_STORE(acc3, 3)
#undef POOL_STORE
        __syncthreads();

        // coalesced drain: 512 ushort4 chunks (32 u x 4 bat x 4), 2/thread
#pragma unroll
        for (int it = 0; it < 2; ++it) {
            const int idx = tid + 256 * it;
            const int du  = idx >> 4;            // u-local 0..31
            const int bat = (idx >> 2) & 3;
            const int dc  = idx & 3;
            const int ug  = ubase + du;
            const int wq  = w0 + 4 * dc;
            if (ug < U_ && wq + 4 <= P_) {
                const ushort4 st = *(const ushort4*)&stage[du][bat * 16 + 4 * dc];
                *(ushort4*)&pooled[((size_t)ug * B_ + (b0 + bat)) * P_ + wq] = st;
            }
        }
        __syncthreads();   // stage reused next ntp
    }
}

// ---------------------------------------------------------------------------
// fc_mfma_k: per-unit FC1 via MFMA + BN2+ReLU+FC2+BN3+ReLU -> zT (B,304)
// A-loads issued upfront (latency hides under w staging). 1-D grid 600,
// XCD-swizzled. 4 waves = 4 m-tiles x all 4 n-tiles. B: raw w_fc1 staged to
// LDS as bf16 (unscaled); BN2 scale applied in f32 epilogue.
// ---------------------------------------------------------------------------
__global__ __launch_bounds__(256, 3)
void fc_mfma_k(const ushort_t* __restrict__ pooled,  // (U,B,P) bf16
               const float* __restrict__ w_fc1,      // (U,FC,P) f32
               const float* __restrict__ b_fc1,
               const float* __restrict__ g2,
               const float* __restrict__ be2,
               const float* __restrict__ m2,
               const float* __restrict__ v2,
               const float* __restrict__ w_fc2,
               const float* __restrict__ b_fc2,
               const float* __restrict__ g3,
               const float* __restrict__ be3,
               const float* __restrict__ m3,
               const float* __restrict__ v3,
               float* __restrict__ zT)               // (B,304)
{
    __shared__ ushort_t wlds[FC_ * WLD_];  // 100 rows x 144 bf16 = 28.8 KB
    __shared__ float zred[128][33];
    const int tid  = threadIdx.x;
    // XCD-swizzle decode: u<296: bid = (u%8) + 8*((u/8)*2 + bt); tail appended
    const int bid = blockIdx.x;
    int u, bt;
    if (bid < 592) {
        const int r = bid & 7, k = bid >> 3;
        bt = k & 1;
        u  = (k >> 1) * 8 + r;
    } else {
        const int t = bid - 592;
        u  = 296 + (t >> 1);
        bt = t & 1;
    }

    const int lane = tid & 63;
    const int wv   = tid >> 6;            // m-tile within the 128-batch panel
    const int half = lane >> 5;
    const int r32  = lane & 31;

    // issue ALL A-loads first (latency hides under w staging below)
    const int brow = bt * 128 + wv * 32 + r32;
    const ushort_t* __restrict__ abase =
        pooled + ((size_t)u * B_ + brow) * P_ + half * 8;
    short8v a[9];
#pragma unroll
    for (int kc = 0; kc < 9; ++kc)
        a[kc] = *(const short8v*)(abase + kc * 16);

    // stage raw w_fc1 panel -> bf16 LDS (coalesced float4 reads)
    const float* __restrict__ wsrc = w_fc1 + (size_t)u * FC_ * P_;
    for (int idx = tid; idx < FC_ * 35; idx += 256) {
        const int f = idx / 35, j = idx - f * 35;
        const float4 v = *(const float4*)(wsrc + f * P_ + 4 * j);
        ushort4 pk;
        pk.x = f2bf(v.x); pk.y = f2bf(v.y); pk.z = f2bf(v.z); pk.w = f2bf(v.w);
        *(ushort4*)&wlds[f * WLD_ + 4 * j] = pk;
    }
    for (int idx = tid; idx < FC_ * 4; idx += 256) {
        const int f = idx >> 2, k = 140 + (idx & 3);
        wlds[f * WLD_ + k] = 0;
    }
    __syncthreads();

    const ushort_t* __restrict__ bl0 = &wlds[r32 * WLD_ + half * 8];
    const ushort_t* __restrict__ bl1 = &wlds[(32 + r32) * WLD_ + half * 8];
    const ushort_t* __restrict__ bl2 = &wlds[(64 + r32) * WLD_ + half * 8];
    const int f3c = (96 + r32 < FC_) ? (96 + r32) : (FC_ - 1);   // clamp
    const ushort_t* __restrict__ bl3 = &wlds[f3c * WLD_ + half * 8];

    f32x16 acc0 = {}, acc1 = {}, acc2 = {}, acc3 = {};
#pragma unroll
    for (int kc = 0; kc < 9; ++kc) {
        const short8v b0 = *(const short8v*)(bl0 + kc * 16);
        const short8v b1 = *(const short8v*)(bl1 + kc * 16);
        const short8v b2 = *(const short8v*)(bl2 + kc * 16);
        const short8v b3 = *(const short8v*)(bl3 + kc * 16);
        acc0 = __builtin_amdgcn_mfma_f32_32x32x16_bf16(a[kc], b0, acc0, 0, 0, 0);
        acc1 = __builtin_amdgcn_mfma_f32_32x32x16_bf16(a[kc], b1, acc1, 0, 0, 0);
        acc2 = __builtin_amdgcn_mfma_f32_32x32x16_bf16(a[kc], b2, acc2, 0, 0, 0);
        acc3 = __builtin_amdgcn_mfma_f32_32x32x16_bf16(a[kc], b3, acc3, 0, 0, 0);
    }

    // inline BN2 params per lane (4 f-columns)
    float s2[4], o2[4], w2[4];
#pragma unroll
    for (int n = 0; n < 4; ++n) {
        const int f = n * 32 + r32;
        if (f < FC_) {
            const int fg = u * FC_ + f;
            const float ss = g2[fg] / sqrtf(v2[fg] + EPS_);
            s2[n] = ss;
            o2[n] = (b_fc1[fg] - m2[fg]) * ss + be2[fg];
            w2[n] = w_fc2[fg];
        } else {
            s2[n] = 0.f; o2[n] = 0.f; w2[n] = 0.f;
        }
    }
#pragma unroll
    for (int rg = 0; rg < 16; ++rg) {
        const int row = (rg & 3) + 8 * (rg >> 2) + 4 * half;
        float s = fmaxf(fmaf(acc0[rg], s2[0], o2[0]), 0.f) * w2[0];
        s = fmaf(fmaxf(fmaf(acc1[rg], s2[1], o2[1]), 0.f), w2[1], s);
        s = fmaf(fmaxf(fmaf(acc2[rg], s2[2], o2[2]), 0.f), w2[2], s);
        s = fmaf(fmaxf(fmaf(acc3[rg], s2[3], o2[3]), 0.f), w2[3], s);
        zred[wv * 32 + row][r32] = s;
    }
    __syncthreads();

    // reduce 32 lane-partials per batch row; write transposed (B,304)
    if (tid < 128) {
        float s = 0.f;
#pragma unroll
        for (int j = 0; j < 32; ++j) s += zred[tid][j];
        const float s3 = g3[u] / sqrtf(v3[u] + EPS_);
        const float o3 = (b_fc2[u] - m3[u]) * s3 + be3[u];
        zT[(size_t)(bt * 128 + tid) * 304 + u] = fmaxf(fmaf(s, s3, o3), 0.f);
    }
}

// ---------------------------------------------------------------------------
// out_k: out[b] = sigmoid( dot(zT[b,0:300], w_out) + b_out ), coalesced f4.
// ---------------------------------------------------------------------------
__global__ __launch_bounds__(64, 8)
void out_k(const float* __restrict__ zT,      // (B,304)
           const float* __restrict__ w_out,   // (U,1)
           const float* __restrict__ b_out,   // (1,)
           float* __restrict__ out)           // (B,1)
{
    const int lane = threadIdx.x;
    const int b    = blockIdx.x;
    const float4* zr = (const float4*)(zT + (size_t)b * 304);
    const float4* w4 = (const float4*)w_out;

    float s = 0.f;
    for (int i = lane; i < 75; i += 64) {
        const float4 z = zr[i], w = w4[i];
        s += z.x * w.x + z.y * w.y + z.z * w.z + z.w * w.w;
    }
#pragma unroll
    for (int o = 32; o > 0; o >>= 1) s += __shfl_xor(s, o);
    if (lane == 0)
        out[b] = 1.0f / (1.0f + __expf(-(s + b_out[0])));
}

// ---------------------------------------------------------------------------
extern "C" void kernel_launch(void* const* d_in, const int* in_sizes, int n_in,
                              void* d_out, int out_size, void* d_ws, size_t ws_size,
                              hipStream_t stream)
{
    const float* input_seq = (const float*)d_in[0];   // (B,L,4)
    const float* w_conv    = (const float*)d_in[1];
    const float* b_conv    = (const float*)d_in[2];
    const float* g1        = (const float*)d_in[3];
    const float* be1       = (const float*)d_in[4];
    const float* m1        = (const float*)d_in[5];
    const float* v1        = (const float*)d_in[6];
    const float* w_fc1     = (const float*)d_in[7];
    const float* b_fc1     = (const float*)d_in[8];
    const float* g2        = (const float*)d_in[9];
    const float* be2       = (const float*)d_in[10];
    const float* m2        = (const float*)d_in[11];
    const float* v2        = (const float*)d_in[12];
    const float* w_fc2     = (const float*)d_in[13];
    const float* b_fc2     = (const float*)d_in[14];
    const float* g3        = (const float*)d_in[15];
    const float* be3       = (const float*)d_in[16];
    const float* m3        = (const float*)d_in[17];
    const float* v3        = (const float*)d_in[18];
    const float* w_out     = (const float*)d_in[19];
    const float* b_out     = (const float*)d_in[20];

    // Workspace layout (~21.9 MB of ws):
    char* p = (char*)d_ws;
    ushort_t* pooled = (ushort_t*)p;   p += (size_t)B_ * U_ * P_ * 2;   // 21,504,000
    ushort_t* w_bf   = (ushort_t*)p;   p += 320 * 80 * 2;               //     51,200
    float*    o1g    = (float*)p;      p += 320 * 4;                    //      1,280
    float*    zT     = (float*)p;      p += (size_t)B_ * 304 * 4;       //    311,296

    pack_conv_k<<<dim3(100), 256, 0, stream>>>(
        w_conv, b_conv, g1, be1, m1, v1, w_bf, o1g);

    conv_mfma_k<<<dim3(9, 2, B_ / 4), 256, 0, stream>>>(
        (const float4*)input_seq, w_bf, o1g, pooled);

    fc_mfma_k<<<dim3(600), 256, 0, stream>>>(
        pooled, w_fc1, b_fc1, g2, be2, m2, v2, w_fc2, b_fc2,
        g3, be3, m3, v3, zT);

    out_k<<<dim3(B_), 64, 0, stream>>>(zT, w_out, b_out, (float*)d_out);
}

// Round 22
// 56.314 us; speedup vs baseline: 1.5971x; 1.5971x over previous
//
#include <hip/hip_runtime.h>
#include <hip/hip_bf16.h>
#include <math.h>

// Problem constants
#define U_   300
#define K_   19
#define FC_  100
#define B_   256
#define L_   1000
#define P_   140     // pooled length
#define EPS_ 1e-5f
#define WLD_ 144     // fc LDS row stride (bf16): 288 B, 16-B aligned

typedef unsigned short ushort_t;
typedef __attribute__((ext_vector_type(8)))  short short8v;   // 8 bf16 = 4 VGPR
typedef __attribute__((ext_vector_type(16))) float f32x16;    // MFMA 32x32 acc

// f32 -> bf16 round-to-nearest-even (bit trick)
__device__ __forceinline__ ushort_t f2bf(float f) {
    union { float f; unsigned u; } a; a.f = f;
    unsigned r = a.u + 0x7fffu + ((a.u >> 16) & 1u);
    return (ushort_t)(r >> 16);
}

// ---------------------------------------------------------------------------
// pack_conv_k: conv weights -> bf16, BN1 scale folded, LANE-LINEAR tile layout:
//   element offset = nt*2560 + kc*512 + half*256 + r*8 + e
// (u = nt*32 + r, GEMM-k j = kc*16 + half*8 + e, j order = 4*t + d).
// Lane (half*32+r) reads its 16 B at byte offset lane*16 in the (nt,kc) slab.
// ---------------------------------------------------------------------------
__global__ __launch_bounds__(256, 4)
void pack_conv_k(const float* __restrict__ w_conv, const float* __restrict__ b_conv,
                 const float* __restrict__ g1, const float* __restrict__ be1,
                 const float* __restrict__ m1, const float* __restrict__ v1,
                 ushort_t* __restrict__ w_bf, float* __restrict__ o1g)
{
    const int t = blockIdx.x * 256 + threadIdx.x;
    if (t < 320 * 80) {
        const int u = t / 80, j = t - u * 80;
        float val = 0.f;
        if (u < U_ && j < 76) {
            const int tp = j >> 2;          // kernel position 0..18
            const int d  = j & 3;           // DNA channel 0..3
            const float s1 = g1[u] / sqrtf(v1[u] + EPS_);
            val = w_conv[u * 76 + 19 * d + tp] * s1;
        }
        const int nt = u >> 5, r = u & 31;
        const int kc = j >> 4, rem = j & 15;
        const int half = rem >> 3, e = rem & 7;
        w_bf[nt * 2560 + kc * 512 + half * 256 + r * 8 + e] = f2bf(val);
    }
    if (t < 320) {
        float o = 0.f;
        if (t < U_) {
            const float s1 = g1[t] / sqrtf(v1[t] + EPS_);
            o = (b_conv[t] - m1[t]) * s1 + be1[t];
        }
        o1g[t] = o;
    }
}

// ---------------------------------------------------------------------------
// conv_mfma_k R22: R20 small-block structure + FULL-CACHE-LINE writes.
// Block covers 32 windows (64 B per (u,b) pooled row = exactly one line;
// R20's 16-window blocks produced half-line writes -> WRITE_SIZE 35-40 MB
// for a 21.5-MB buffer, the one anomaly surviving all variants).
// 512 threads = 8 waves = 8 m-tiles (4 windows each); grid (5 bx, 2 nh, 256 b);
// bx=4 has 12 live windows (guarded). x staged once (244 rows); B-frags per
// ntp from the L2-resident lane-linear table; in-register pooling via row
// permutation; per-ntp stage + 64-B-per-row coalesced drain.
// ~80 VGPR, LDS ~4.1 KB -> 3 blocks/CU = 24 waves/CU.
// ---------------------------------------------------------------------------
__global__ __launch_bounds__(512, 3)
void conv_mfma_k(const float4* __restrict__ x4,        // (B,1000) float4 (D=4)
                 const ushort_t* __restrict__ w_bf,    // packed tiles (see pack)
                 const float* __restrict__ o1g,        // (320)
                 ushort_t* __restrict__ pooled)        // (U,B,P) bf16
{
    __shared__ ushort_t xls[976];        // bf16 x_flat rows l0..l0+243
    __shared__ ushort_t stage[32][34];   // [u-local][32 windows], 17-word rows
    const int tid = threadIdx.x;
    const int bx  = blockIdx.x;          // 0..4
    const int nh  = blockIdx.y;          // 0/1 -> nt range [5nh, 5nh+5)
    const int b   = blockIdx.z;          // batch
    const int w0  = bx * 32;             // first window of block
    const int l0  = w0 * 7;              // first conv row (224*bx, max 896)

    // stage x rows as bf16 (max row needed: 28*7+46+18 = 242 -> 244; guard L)
    if (tid < 244) {
        const int gi = l0 + tid;
        float4 v = make_float4(0.f, 0.f, 0.f, 0.f);
        if (gi < L_) v = x4[(size_t)b * L_ + gi];
        ushort4 pk4;
        pk4.x = f2bf(v.x); pk4.y = f2bf(v.y); pk4.z = f2bf(v.z); pk4.w = f2bf(v.w);
        *(ushort4*)&xls[4 * tid] = pk4;
    }
    __syncthreads();

    const int lane = tid & 63;
    const int wv   = tid >> 6;           // m-tile 0..7 (windows 4wv..4wv+3)
    const int half = lane >> 5;
    const int r32  = lane & 31;

    // permuted A-row offset for slot r32 (two 7-row pool windows per
    // lane-half's C slots; spares at sreg 14,15)
    const int sreg = (r32 & 3) + 4 * (r32 >> 3);
    const int sh   = (r32 >> 2) & 1;
    const int off  = sreg < 7  ? sreg + 7 * sh
                   : sreg < 14 ? sreg + 7 + 7 * sh
                               : 28 + (sreg - 14) + 2 * sh;

    const char* xb = (const char*)xls + 8 * (28 * wv + off) + 16 * half;

    // hoist nt-invariant A-fragments into registers (20 VGPR)
    short8v aA[5];
#pragma unroll
    for (int kc = 0; kc < 5; ++kc)
        aA[kc] = *(const short8v*)(xb + 32 * kc);

    // lane-linear B base in the packed global table (L2-resident, 51 KB)
    const char* wgl = (const char*)w_bf + nh * 5 * 5120 + 16 * lane;

    const int p0off = 4 * wv + half;     // stage cols p0off, p0off+2

    for (int ntp = 0; ntp < 5; ++ntp) {
        short8v bfr[5];
#pragma unroll
        for (int kc = 0; kc < 5; ++kc)
            bfr[kc] = *(const short8v*)(wgl + ntp * 5120 + kc * 1024);
        const int ubase = nh * 160 + ntp * 32;
        const float o1u = o1g[ubase + r32];

        f32x16 acc = {};
#pragma unroll
        for (int kc = 0; kc < 5; ++kc)
            acc = __builtin_amdgcn_mfma_f32_32x32x16_bf16(aA[kc], bfr[kc], acc, 0, 0, 0);

        // in-register pooling (o1 added after max; exp monotone)
        float m0 = acc[0], m1 = acc[7];
#pragma unroll
        for (int j = 1; j < 7; ++j)  m0 = fmaxf(m0, acc[j]);
#pragma unroll
        for (int j = 8; j < 14; ++j) m1 = fmaxf(m1, acc[j]);

        // stage (row stride 17 words, coprime 32 -> conflict-free)
        stage[r32][p0off]     = f2bf(__expf(m0 + o1u));
        stage[r32][p0off + 2] = f2bf(__expf(m1 + o1u));
        __syncthreads();

        // drain: 256 threads x 1 ushort4; 8 consecutive lanes = one 64-B
        // fully-populated cache line of a single (u,b) pooled row
        if (tid < 256) {
            const int du = tid >> 3, dc = tid & 7;
            const int ug = ubase + du;
            const int wq = w0 + 4 * dc;
            if (ug < U_ && wq + 4 <= P_) {
                const ushort4 st = *(const ushort4*)&stage[du][4 * dc];
                *(ushort4*)&pooled[((size_t)ug * B_ + b) * P_ + wq] = st;
            }
        }
        __syncthreads();   // stage reused next ntp
    }
}

// ---------------------------------------------------------------------------
// fc_mfma_k: per-unit FC1 via MFMA + BN2+ReLU+FC2+BN3+ReLU -> zT (B,304)
// A-loads issued upfront (latency hides under w staging). 1-D grid 600,
// XCD-swizzled. 4 waves = 4 m-tiles x all 4 n-tiles. B: raw w_fc1 staged to
// LDS as bf16 (unscaled); BN2 scale applied in f32 epilogue.
// ---------------------------------------------------------------------------
__global__ __launch_bounds__(256, 3)
void fc_mfma_k(const ushort_t* __restrict__ pooled,  // (U,B,P) bf16
               const float* __restrict__ w_fc1,      // (U,FC,P) f32
               const float* __restrict__ b_fc1,
               const float* __restrict__ g2,
               const float* __restrict__ be2,
               const float* __restrict__ m2,
               const float* __restrict__ v2,
               const float* __restrict__ w_fc2,
               const float* __restrict__ b_fc2,
               const float* __restrict__ g3,
               const float* __restrict__ be3,
               const float* __restrict__ m3,
               const float* __restrict__ v3,
               float* __restrict__ zT)               // (B,304)
{
    __shared__ ushort_t wlds[FC_ * WLD_];  // 100 rows x 144 bf16 = 28.8 KB
    __shared__ float zred[128][33];
    const int tid  = threadIdx.x;
    // XCD-swizzle decode: u<296: bid = (u%8) + 8*((u/8)*2 + bt); tail appended
    const int bid = blockIdx.x;
    int u, bt;
    if (bid < 592) {
        const int r = bid & 7, k = bid >> 3;
        bt = k & 1;
        u  = (k >> 1) * 8 + r;
    } else {
        const int t = bid - 592;
        u  = 296 + (t >> 1);
        bt = t & 1;
    }

    const int lane = tid & 63;
    const int wv   = tid >> 6;            // m-tile within the 128-batch panel
    const int half = lane >> 5;
    const int r32  = lane & 31;

    // issue ALL A-loads first (latency hides under w staging below)
    const int brow = bt * 128 + wv * 32 + r32;
    const ushort_t* __restrict__ abase =
        pooled + ((size_t)u * B_ + brow) * P_ + half * 8;
    short8v a[9];
#pragma unroll
    for (int kc = 0; kc < 9; ++kc)
        a[kc] = *(const short8v*)(abase + kc * 16);

    // stage raw w_fc1 panel -> bf16 LDS (coalesced float4 reads)
    const float* __restrict__ wsrc = w_fc1 + (size_t)u * FC_ * P_;
    for (int idx = tid; idx < FC_ * 35; idx += 256) {
        const int f = idx / 35, j = idx - f * 35;
        const float4 v = *(const float4*)(wsrc + f * P_ + 4 * j);
        ushort4 pk;
        pk.x = f2bf(v.x); pk.y = f2bf(v.y); pk.z = f2bf(v.z); pk.w = f2bf(v.w);
        *(ushort4*)&wlds[f * WLD_ + 4 * j] = pk;
    }
    for (int idx = tid; idx < FC_ * 4; idx += 256) {
        const int f = idx >> 2, k = 140 + (idx & 3);
        wlds[f * WLD_ + k] = 0;
    }
    __syncthreads();

    const ushort_t* __restrict__ bl0 = &wlds[r32 * WLD_ + half * 8];
    const ushort_t* __restrict__ bl1 = &wlds[(32 + r32) * WLD_ + half * 8];
    const ushort_t* __restrict__ bl2 = &wlds[(64 + r32) * WLD_ + half * 8];
    const int f3c = (96 + r32 < FC_) ? (96 + r32) : (FC_ - 1);   // clamp
    const ushort_t* __restrict__ bl3 = &wlds[f3c * WLD_ + half * 8];

    f32x16 acc0 = {}, acc1 = {}, acc2 = {}, acc3 = {};
#pragma unroll
    for (int kc = 0; kc < 9; ++kc) {
        const short8v b0 = *(const short8v*)(bl0 + kc * 16);
        const short8v b1 = *(const short8v*)(bl1 + kc * 16);
        const short8v b2 = *(const short8v*)(bl2 + kc * 16);
        const short8v b3 = *(const short8v*)(bl3 + kc * 16);
        acc0 = __builtin_amdgcn_mfma_f32_32x32x16_bf16(a[kc], b0, acc0, 0, 0, 0);
        acc1 = __builtin_amdgcn_mfma_f32_32x32x16_bf16(a[kc], b1, acc1, 0, 0, 0);
        acc2 = __builtin_amdgcn_mfma_f32_32x32x16_bf16(a[kc], b2, acc2, 0, 0, 0);
        acc3 = __builtin_amdgcn_mfma_f32_32x32x16_bf16(a[kc], b3, acc3, 0, 0, 0);
    }

    // inline BN2 params per lane (4 f-columns)
    float s2[4], o2[4], w2[4];
#pragma unroll
    for (int n = 0; n < 4; ++n) {
        const int f = n * 32 + r32;
        if (f < FC_) {
            const int fg = u * FC_ + f;
            const float ss = g2[fg] / sqrtf(v2[fg] + EPS_);
            s2[n] = ss;
            o2[n] = (b_fc1[fg] - m2[fg]) * ss + be2[fg];
            w2[n] = w_fc2[fg];
        } else {
            s2[n] = 0.f; o2[n] = 0.f; w2[n] = 0.f;
        }
    }
#pragma unroll
    for (int rg = 0; rg < 16; ++rg) {
        const int row = (rg & 3) + 8 * (rg >> 2) + 4 * half;
        float s = fmaxf(fmaf(acc0[rg], s2[0], o2[0]), 0.f) * w2[0];
        s = fmaf(fmaxf(fmaf(acc1[rg], s2[1], o2[1]), 0.f), w2[1], s);
        s = fmaf(fmaxf(fmaf(acc2[rg], s2[2], o2[2]), 0.f), w2[2], s);
        s = fmaf(fmaxf(fmaf(acc3[rg], s2[3], o2[3]), 0.f), w2[3], s);
        zred[wv * 32 + row][r32] = s;
    }
    __syncthreads();

    // reduce 32 lane-partials per batch row; write transposed (B,304)
    if (tid < 128) {
        float s = 0.f;
#pragma unroll
        for (int j = 0; j < 32; ++j) s += zred[tid][j];
        const float s3 = g3[u] / sqrtf(v3[u] + EPS_);
        const float o3 = (b_fc2[u] - m3[u]) * s3 + be3[u];
        zT[(size_t)(bt * 128 + tid) * 304 + u] = fmaxf(fmaf(s, s3, o3), 0.f);
    }
}

// ---------------------------------------------------------------------------
// out_k: out[b] = sigmoid( dot(zT[b,0:300], w_out) + b_out ), coalesced f4.
// ---------------------------------------------------------------------------
__global__ __launch_bounds__(64, 8)
void out_k(const float* __restrict__ zT,      // (B,304)
           const float* __restrict__ w_out,   // (U,1)
           const float* __restrict__ b_out,   // (1,)
           float* __restrict__ out)           // (B,1)
{
    const int lane = threadIdx.x;
    const int b    = blockIdx.x;
    const float4* zr = (const float4*)(zT + (size_t)b * 304);
    const float4* w4 = (const float4*)w_out;

    float s = 0.f;
    for (int i = lane; i < 75; i += 64) {
        const float4 z = zr[i], w = w4[i];
        s += z.x * w.x + z.y * w.y + z.z * w.z + z.w * w.w;
    }
#pragma unroll
    for (int o = 32; o > 0; o >>= 1) s += __shfl_xor(s, o);
    if (lane == 0)
        out[b] = 1.0f / (1.0f + __expf(-(s + b_out[0])));
}

// ---------------------------------------------------------------------------
extern "C" void kernel_launch(void* const* d_in, const int* in_sizes, int n_in,
                              void* d_out, int out_size, void* d_ws, size_t ws_size,
                              hipStream_t stream)
{
    const float* input_seq = (const float*)d_in[0];   // (B,L,4)
    const float* w_conv    = (const float*)d_in[1];
    const float* b_conv    = (const float*)d_in[2];
    const float* g1        = (const float*)d_in[3];
    const float* be1       = (const float*)d_in[4];
    const float* m1        = (const float*)d_in[5];
    const float* v1        = (const float*)d_in[6];
    const float* w_fc1     = (const float*)d_in[7];
    const float* b_fc1     = (const float*)d_in[8];
    const float* g2        = (const float*)d_in[9];
    const float* be2       = (const float*)d_in[10];
    const float* m2        = (const float*)d_in[11];
    const float* v2        = (const float*)d_in[12];
    const float* w_fc2     = (const float*)d_in[13];
    const float* b_fc2     = (const float*)d_in[14];
    const float* g3        = (const float*)d_in[15];
    const float* be3       = (const float*)d_in[16];
    const float* m3        = (const float*)d_in[17];
    const float* v3        = (const float*)d_in[18];
    const float* w_out     = (const float*)d_in[19];
    const float* b_out     = (const float*)d_in[20];

    // Workspace layout (~21.9 MB of ws):
    char* p = (char*)d_ws;
    ushort_t* pooled = (ushort_t*)p;   p += (size_t)B_ * U_ * P_ * 2;   // 21,504,000
    ushort_t* w_bf   = (ushort_t*)p;   p += 320 * 80 * 2;               //     51,200
    float*    o1g    = (float*)p;      p += 320 * 4;                    //      1,280
    float*    zT     = (float*)p;      p += (size_t)B_ * 304 * 4;       //    311,296

    pack_conv_k<<<dim3(100), 256, 0, stream>>>(
        w_conv, b_conv, g1, be1, m1, v1, w_bf, o1g);

    conv_mfma_k<<<dim3(5, 2, B_), 512, 0, stream>>>(
        (const float4*)input_seq, w_bf, o1g, pooled);

    fc_mfma_k<<<dim3(600), 256, 0, stream>>>(
        pooled, w_fc1, b_fc1, g2, be2, m2, v2, w_fc2, b_fc2,
        g3, be3, m3, v3, zT);

    out_k<<<dim3(B_), 64, 0, stream>>>(zT, w_out, b_out, (float*)d_out);
}

// Round 23
// 53.220 us; speedup vs baseline: 1.6900x; 1.0581x over previous
//
#include <hip/hip_runtime.h>
#include <hip/hip_bf16.h>
#include <math.h>

// Problem constants
#define U_   300
#define K_   19
#define FC_  100
#define B_   256
#define L_   1000
#define P_   140     // pooled length
#define EPS_ 1e-5f
#define WLD_ 144     // fc LDS row stride (bf16): 288 B, 16-B aligned

typedef unsigned short ushort_t;
typedef __attribute__((ext_vector_type(8)))  short short8v;   // 8 bf16 = 4 VGPR
typedef __attribute__((ext_vector_type(16))) float f32x16;    // MFMA 32x32 acc

// f32 -> bf16 round-to-nearest-even (bit trick)
__device__ __forceinline__ ushort_t f2bf(float f) {
    union { float f; unsigned u; } a; a.f = f;
    unsigned r = a.u + 0x7fffu + ((a.u >> 16) & 1u);
    return (ushort_t)(r >> 16);
}

// ---------------------------------------------------------------------------
// pack_conv_k: conv weights -> bf16, BN1 scale folded, LANE-LINEAR tile layout:
//   element offset = nt*2560 + kc*512 + half*256 + r*8 + e
// (u = nt*32 + r, GEMM-k j = kc*16 + half*8 + e, j order = 4*t + d).
// Lane (half*32+r) reads its 16 B at byte offset lane*16 in the (nt,kc) slab.
// ---------------------------------------------------------------------------
__global__ __launch_bounds__(256, 4)
void pack_conv_k(const float* __restrict__ w_conv, const float* __restrict__ b_conv,
                 const float* __restrict__ g1, const float* __restrict__ be1,
                 const float* __restrict__ m1, const float* __restrict__ v1,
                 ushort_t* __restrict__ w_bf, float* __restrict__ o1g)
{
    const int t = blockIdx.x * 256 + threadIdx.x;
    if (t < 320 * 80) {
        const int u = t / 80, j = t - u * 80;
        float val = 0.f;
        if (u < U_ && j < 76) {
            const int tp = j >> 2;          // kernel position 0..18
            const int d  = j & 3;           // DNA channel 0..3
            const float s1 = g1[u] / sqrtf(v1[u] + EPS_);
            val = w_conv[u * 76 + 19 * d + tp] * s1;
        }
        const int nt = u >> 5, r = u & 31;
        const int kc = j >> 4, rem = j & 15;
        const int half = rem >> 3, e = rem & 7;
        w_bf[nt * 2560 + kc * 512 + half * 256 + r * 8 + e] = f2bf(val);
    }
    if (t < 320) {
        float o = 0.f;
        if (t < U_) {
            const float s1 = g1[t] / sqrtf(v1[t] + EPS_);
            o = (b_conv[t] - m1[t]) * s1 + be1[t];
        }
        o1g[t] = o;
    }
}

// ---------------------------------------------------------------------------
// conv_mfma_k (R20 best config): SMALL BLOCKS, HIGH OCCUPANCY.
// 256 threads = 4 waves = 4 m-tiles (4 windows each); block covers 16 windows.
// Grid (9 bx, 2 nh, 256 b); bx=8 has 12 live windows (guarded).
// LDS ~3.3 KB, ~80 VGPR -> high waves/SIMD; B-frags from the L2-resident
// lane-linear table per ntp; x staged once; in-register pooling via row
// permutation; per-ntp LDS stage + drain (ushort4 = 4 windows per store).
// ---------------------------------------------------------------------------
__global__ __launch_bounds__(256, 6)
void conv_mfma_k(const float4* __restrict__ x4,        // (B,1000) float4 (D=4)
                 const ushort_t* __restrict__ w_bf,    // packed tiles (see pack)
                 const float* __restrict__ o1g,        // (320)
                 ushort_t* __restrict__ pooled)        // (U,B,P) bf16
{
    __shared__ ushort_t xls[544];        // bf16 x_flat rows l0..l0+135
    __shared__ ushort_t stage[32][18];   // [u-local][16 windows]; 9-word rows
    const int tid = threadIdx.x;
    const int bx  = blockIdx.x;          // 0..8
    const int nh  = blockIdx.y;          // 0/1 -> nt range [5nh, 5nh+5)
    const int b   = blockIdx.z;          // batch
    const int w0  = bx * 16;             // first window of block
    const int l0  = w0 * 7;              // first conv row (112*bx, max 896)

    // stage x rows as bf16 (rows needed: up to 28*3+31+18 = 133 -> 136)
    if (tid < 136) {
        const int gi = l0 + tid;
        float4 v = make_float4(0.f, 0.f, 0.f, 0.f);
        if (gi < L_) v = x4[(size_t)b * L_ + gi];
        ushort4 pk4;
        pk4.x = f2bf(v.x); pk4.y = f2bf(v.y); pk4.z = f2bf(v.z); pk4.w = f2bf(v.w);
        *(ushort4*)&xls[4 * tid] = pk4;
    }
    __syncthreads();

    const int lane = tid & 63;
    const int wv   = tid >> 6;           // m-tile 0..3 (windows 4wv..4wv+3)
    const int half = lane >> 5;
    const int r32  = lane & 31;

    // permuted A-row offset for slot r32 (two 7-row pool windows per
    // lane-half's C slots; spares at sreg 14,15)
    const int sreg = (r32 & 3) + 4 * (r32 >> 3);
    const int sh   = (r32 >> 2) & 1;
    const int off  = sreg < 7  ? sreg + 7 * sh
                   : sreg < 14 ? sreg + 7 + 7 * sh
                               : 28 + (sreg - 14) + 2 * sh;

    const char* xb = (const char*)xls + 8 * (28 * wv + off) + 16 * half;

    // hoist nt-invariant A-fragments into registers (20 VGPR)
    short8v aA[5];
#pragma unroll
    for (int kc = 0; kc < 5; ++kc)
        aA[kc] = *(const short8v*)(xb + 32 * kc);

    // lane-linear B base in the packed global table (L2-resident, 51 KB)
    const char* wgl = (const char*)w_bf + nh * 5 * 5120 + 16 * lane;

    const int p0off = 4 * wv + half;     // stage cols p0off, p0off+2

    for (int ntp = 0; ntp < 5; ++ntp) {
        short8v bfr[5];
#pragma unroll
        for (int kc = 0; kc < 5; ++kc)
            bfr[kc] = *(const short8v*)(wgl + ntp * 5120 + kc * 1024);
        const int ubase = nh * 160 + ntp * 32;
        const float o1u = o1g[ubase + r32];

        f32x16 acc = {};
#pragma unroll
        for (int kc = 0; kc < 5; ++kc)
            acc = __builtin_amdgcn_mfma_f32_32x32x16_bf16(aA[kc], bfr[kc], acc, 0, 0, 0);

        // in-register pooling (o1 added after max; exp monotone)
        float m0 = acc[0], m1 = acc[7];
#pragma unroll
        for (int j = 1; j < 7; ++j)  m0 = fmaxf(m0, acc[j]);
#pragma unroll
        for (int j = 8; j < 14; ++j) m1 = fmaxf(m1, acc[j]);

        // stage (row stride 9 words, coprime 32 -> conflict-free)
        stage[r32][p0off]     = f2bf(__expf(m0 + o1u));
        stage[r32][p0off + 2] = f2bf(__expf(m1 + o1u));
        __syncthreads();

        // drain: 128 threads x 1 ushort4 (4 windows) each
        if (tid < 128) {
            const int du = tid >> 2, dc = tid & 3;
            const int ug = ubase + du;
            const int wq = w0 + 4 * dc;
            if (ug < U_ && wq + 3 < P_) {
                const ushort4 st = *(const ushort4*)&stage[du][4 * dc];
                *(ushort4*)&pooled[((size_t)ug * B_ + b) * P_ + wq] = st;
            }
        }
        __syncthreads();   // stage reused next ntp
    }
}

// ---------------------------------------------------------------------------
// fc_mfma_k: per-unit FC1 via MFMA + BN2+ReLU+FC2+BN3+ReLU -> zT (B,304)
// A-loads issued upfront (latency hides under w staging). 1-D grid 600,
// XCD-swizzled. 4 waves = 4 m-tiles x all 4 n-tiles. B: raw w_fc1 staged to
// LDS as bf16 (unscaled); BN2 scale applied in f32 epilogue.
// ---------------------------------------------------------------------------
__global__ __launch_bounds__(256, 3)
void fc_mfma_k(const ushort_t* __restrict__ pooled,  // (U,B,P) bf16
               const float* __restrict__ w_fc1,      // (U,FC,P) f32
               const float* __restrict__ b_fc1,
               const float* __restrict__ g2,
               const float* __restrict__ be2,
               const float* __restrict__ m2,
               const float* __restrict__ v2,
               const float* __restrict__ w_fc2,
               const float* __restrict__ b_fc2,
               const float* __restrict__ g3,
               const float* __restrict__ be3,
               const float* __restrict__ m3,
               const float* __restrict__ v3,
               float* __restrict__ zT)               // (B,304)
{
    __shared__ ushort_t wlds[FC_ * WLD_];  // 100 rows x 144 bf16 = 28.8 KB
    __shared__ float zred[128][33];
    const int tid  = threadIdx.x;
    // XCD-swizzle decode: u<296: bid = (u%8) + 8*((u/8)*2 + bt); tail appended
    const int bid = blockIdx.x;
    int u, bt;
    if (bid < 592) {
        const int r = bid & 7, k = bid >> 3;
        bt = k & 1;
        u  = (k >> 1) * 8 + r;
    } else {
        const int t = bid - 592;
        u  = 296 + (t >> 1);
        bt = t & 1;
    }

    const int lane = tid & 63;
    const int wv   = tid >> 6;            // m-tile within the 128-batch panel
    const int half = lane >> 5;
    const int r32  = lane & 31;

    // issue ALL A-loads first (latency hides under w staging below)
    const int brow = bt * 128 + wv * 32 + r32;
    const ushort_t* __restrict__ abase =
        pooled + ((size_t)u * B_ + brow) * P_ + half * 8;
    short8v a[9];
#pragma unroll
    for (int kc = 0; kc < 9; ++kc)
        a[kc] = *(const short8v*)(abase + kc * 16);

    // stage raw w_fc1 panel -> bf16 LDS (coalesced float4 reads)
    const float* __restrict__ wsrc = w_fc1 + (size_t)u * FC_ * P_;
    for (int idx = tid; idx < FC_ * 35; idx += 256) {
        const int f = idx / 35, j = idx - f * 35;
        const float4 v = *(const float4*)(wsrc + f * P_ + 4 * j);
        ushort4 pk;
        pk.x = f2bf(v.x); pk.y = f2bf(v.y); pk.z = f2bf(v.z); pk.w = f2bf(v.w);
        *(ushort4*)&wlds[f * WLD_ + 4 * j] = pk;
    }
    for (int idx = tid; idx < FC_ * 4; idx += 256) {
        const int f = idx >> 2, k = 140 + (idx & 3);
        wlds[f * WLD_ + k] = 0;
    }
    __syncthreads();

    const ushort_t* __restrict__ bl0 = &wlds[r32 * WLD_ + half * 8];
    const ushort_t* __restrict__ bl1 = &wlds[(32 + r32) * WLD_ + half * 8];
    const ushort_t* __restrict__ bl2 = &wlds[(64 + r32) * WLD_ + half * 8];
    const int f3c = (96 + r32 < FC_) ? (96 + r32) : (FC_ - 1);   // clamp
    const ushort_t* __restrict__ bl3 = &wlds[f3c * WLD_ + half * 8];

    f32x16 acc0 = {}, acc1 = {}, acc2 = {}, acc3 = {};
#pragma unroll
    for (int kc = 0; kc < 9; ++kc) {
        const short8v b0 = *(const short8v*)(bl0 + kc * 16);
        const short8v b1 = *(const short8v*)(bl1 + kc * 16);
        const short8v b2 = *(const short8v*)(bl2 + kc * 16);
        const short8v b3 = *(const short8v*)(bl3 + kc * 16);
        acc0 = __builtin_amdgcn_mfma_f32_32x32x16_bf16(a[kc], b0, acc0, 0, 0, 0);
        acc1 = __builtin_amdgcn_mfma_f32_32x32x16_bf16(a[kc], b1, acc1, 0, 0, 0);
        acc2 = __builtin_amdgcn_mfma_f32_32x32x16_bf16(a[kc], b2, acc2, 0, 0, 0);
        acc3 = __builtin_amdgcn_mfma_f32_32x32x16_bf16(a[kc], b3, acc3, 0, 0, 0);
    }

    // inline BN2 params per lane (4 f-columns)
    float s2[4], o2[4], w2[4];
#pragma unroll
    for (int n = 0; n < 4; ++n) {
        const int f = n * 32 + r32;
        if (f < FC_) {
            const int fg = u * FC_ + f;
            const float ss = g2[fg] / sqrtf(v2[fg] + EPS_);
            s2[n] = ss;
            o2[n] = (b_fc1[fg] - m2[fg]) * ss + be2[fg];
            w2[n] = w_fc2[fg];
        } else {
            s2[n] = 0.f; o2[n] = 0.f; w2[n] = 0.f;
        }
    }
#pragma unroll
    for (int rg = 0; rg < 16; ++rg) {
        const int row = (rg & 3) + 8 * (rg >> 2) + 4 * half;
        float s = fmaxf(fmaf(acc0[rg], s2[0], o2[0]), 0.f) * w2[0];
        s = fmaf(fmaxf(fmaf(acc1[rg], s2[1], o2[1]), 0.f), w2[1], s);
        s = fmaf(fmaxf(fmaf(acc2[rg], s2[2], o2[2]), 0.f), w2[2], s);
        s = fmaf(fmaxf(fmaf(acc3[rg], s2[3], o2[3]), 0.f), w2[3], s);
        zred[wv * 32 + row][r32] = s;
    }
    __syncthreads();

    // reduce 32 lane-partials per batch row; write transposed (B,304)
    if (tid < 128) {
        float s = 0.f;
#pragma unroll
        for (int j = 0; j < 32; ++j) s += zred[tid][j];
        const float s3 = g3[u] / sqrtf(v3[u] + EPS_);
        const float o3 = (b_fc2[u] - m3[u]) * s3 + be3[u];
        zT[(size_t)(bt * 128 + tid) * 304 + u] = fmaxf(fmaf(s, s3, o3), 0.f);
    }
}

// ---------------------------------------------------------------------------
// out_k: out[b] = sigmoid( dot(zT[b,0:300], w_out) + b_out ), coalesced f4.
// ---------------------------------------------------------------------------
__global__ __launch_bounds__(64, 8)
void out_k(const float* __restrict__ zT,      // (B,304)
           const float* __restrict__ w_out,   // (U,1)
           const float* __restrict__ b_out,   // (1,)
           float* __restrict__ out)           // (B,1)
{
    const int lane = threadIdx.x;
    const int b    = blockIdx.x;
    const float4* zr = (const float4*)(zT + (size_t)b * 304);
    const float4* w4 = (const float4*)w_out;

    float s = 0.f;
    for (int i = lane; i < 75; i += 64) {
        const float4 z = zr[i], w = w4[i];
        s += z.x * w.x + z.y * w.y + z.z * w.z + z.w * w.w;
    }
#pragma unroll
    for (int o = 32; o > 0; o >>= 1) s += __shfl_xor(s, o);
    if (lane == 0)
        out[b] = 1.0f / (1.0f + __expf(-(s + b_out[0])));
}

// ---------------------------------------------------------------------------
extern "C" void kernel_launch(void* const* d_in, const int* in_sizes, int n_in,
                              void* d_out, int out_size, void* d_ws, size_t ws_size,
                              hipStream_t stream)
{
    const float* input_seq = (const float*)d_in[0];   // (B,L,4)
    const float* w_conv    = (const float*)d_in[1];
    const float* b_conv    = (const float*)d_in[2];
    const float* g1        = (const float*)d_in[3];
    const float* be1       = (const float*)d_in[4];
    const float* m1        = (const float*)d_in[5];
    const float* v1        = (const float*)d_in[6];
    const float* w_fc1     = (const float*)d_in[7];
    const float* b_fc1     = (const float*)d_in[8];
    const float* g2        = (const float*)d_in[9];
    const float* be2       = (const float*)d_in[10];
    const float* m2        = (const float*)d_in[11];
    const float* v2        = (const float*)d_in[12];
    const float* w_fc2     = (const float*)d_in[13];
    const float* b_fc2     = (const float*)d_in[14];
    const float* g3        = (const float*)d_in[15];
    const float* be3       = (const float*)d_in[16];
    const float* m3        = (const float*)d_in[17];
    const float* v3        = (const float*)d_in[18];
    const float* w_out     = (const float*)d_in[19];
    const float* b_out     = (const float*)d_in[20];

    // Workspace layout (~21.9 MB of ws):
    char* p = (char*)d_ws;
    ushort_t* pooled = (ushort_t*)p;   p += (size_t)B_ * U_ * P_ * 2;   // 21,504,000
    ushort_t* w_bf   = (ushort_t*)p;   p += 320 * 80 * 2;               //     51,200
    float*    o1g    = (float*)p;      p += 320 * 4;                    //      1,280
    float*    zT     = (float*)p;      p += (size_t)B_ * 304 * 4;       //    311,296

    pack_conv_k<<<dim3(100), 256, 0, stream>>>(
        w_conv, b_conv, g1, be1, m1, v1, w_bf, o1g);

    conv_mfma_k<<<dim3(9, 2, B_), 256, 0, stream>>>(
        (const float4*)input_seq, w_bf, o1g, pooled);

    fc_mfma_k<<<dim3(600), 256, 0, stream>>>(
        pooled, w_fc1, b_fc1, g2, be2, m2, v2, w_fc2, b_fc2,
        g3, be3, m3, v3, zT);

    out_k<<<dim3(B_), 64, 0, stream>>>(zT, w_out, b_out, (float*)d_out);
}